// Round 10
// baseline (188.826 us; speedup 1.0000x reference)
//
#include <hip/hip_runtime.h>
#include <stdint.h>

typedef unsigned int u32;
typedef unsigned short u16;

#define N_  1024
#define F_  512
#define ALPHA 0.2f
#define TSTR2 72   // k_prep LDS tile stride (u16): 144 B rows -> 16B-aligned b128 reads, 2-way (free)

typedef __attribute__((ext_vector_type(8))) short short8;
typedef __attribute__((ext_vector_type(4))) float float4v;

union Frag { short8 s; u32 u[4]; };

static __device__ __forceinline__ float bits2f(u32 b){ union{u32 u; float f;} c; c.u=b; return c.f; }
static __device__ __forceinline__ u32   f2bits(float f){ union{float f_; u32 u;} c; c.f_=f; return c.u; }
static __device__ __forceinline__ float bflo(u32 p){ return bits2f(p<<16); }
static __device__ __forceinline__ float bfhi(u32 p){ return bits2f(p & 0xffff0000u); }
static __device__ __forceinline__ u32   f2bf(float f){ u32 u=f2bits(f); return (u + 0x7fffu + ((u>>16)&1u))>>16; }
static __device__ __forceinline__ u32   cvt_pk_bf16(float lo, float hi){
    u32 r; asm("v_cvt_pk_bf16_f32 %0, %1, %2" : "=v"(r) : "v"(lo), "v"(hi)); return r;
}

// async global->LDS, 16 B per lane; LDS dest = wave-uniform base + lane*16
static __device__ __forceinline__ void gload_lds16(const void* g, void* l){
    __builtin_amdgcn_global_load_lds((const __attribute__((address_space(1))) u32*)g,
                                     (__attribute__((address_space(3))) u32*)l, 16, 0, 0);
}

// ---- kernel 1: w1 = W^T a1, w2 = W^T a2 (atomic partial sums into ws[0..1024)) ----
__global__ void k_w12(const float* __restrict__ W, const float* __restrict__ a1,
                      const float* __restrict__ a2, float* __restrict__ ws){
    int t = threadIdx.x;          // 256 threads: f = t and t+256
    int bo = blockIdx.x;          // 64 blocks: o-chunk of 8
    float s1a=0.f,s2a=0.f,s1b=0.f,s2b=0.f;
    #pragma unroll
    for(int i=0;i<8;i++){
        int o = bo*8+i;
        float av1 = a1[o], av2 = a2[o];
        float wa = W[o*F_ + t], wb = W[o*F_ + t + 256];
        s1a += wa*av1; s2a += wa*av2; s1b += wb*av1; s2b += wb*av2;
    }
    atomicAdd(&ws[t],       s1a); atomicAdd(&ws[512+t],     s2a);
    atomicAdd(&ws[t+256],   s1b); atomicAdd(&ws[512+t+256], s2b);
}

// ---- kernel 2: transpose X->XT bf16 + d1/d2 dots (R9 known-good, no atomics) ----
__global__ __launch_bounds__(1024)
void k_prep(const float* __restrict__ X, const float* __restrict__ ws,
            u16* __restrict__ XT, float* __restrict__ d1acc, float* __restrict__ d2acc){
    __shared__ u16 tile[4][64][TSTR2];   // 36 KB: [slice-group][f 64][m 64 +pad]
    __shared__ float dpart[2][4][64];    // 2 KB group-partial row dots

    const int t   = threadIdx.x;
    const int id  = blockIdx.x + (blockIdx.y << 4);   // 0..255
    const int xcd = id & 7, slot = id >> 3;
    const int b   = (xcd << 1) | (slot >> 4);
    const int m0  = (slot & 15) << 6;

    const int g    = t >> 8;             // slice group 0..3
    const int tid2 = t & 255;
    const int mg   = tid2 >> 4;          // 0..15
    const int m4   = mg * 4;
    const int fq   = (tid2 & 15) * 4;

    float4 v[2][4];
    #pragma unroll
    for(int p=0;p<2;p++){
        const float* Xb = X + ((size_t)(b*N_ + m0 + m4))*F_ + (p*4+g)*64 + fq;
        #pragma unroll
        for(int i=0;i<4;i++) v[p][i] = *(const float4*)(Xb + (size_t)i*F_);
    }

    float d1p[4]={0.f,0.f,0.f,0.f}, d2p[4]={0.f,0.f,0.f,0.f};
    #pragma unroll
    for(int p=0;p<2;p++){
        float4 w1q = *(const float4*)(ws + (p*4+g)*64 + fq);
        float4 w2q = *(const float4*)(ws + 512 + (p*4+g)*64 + fq);
        #pragma unroll
        for(int i=0;i<4;i++){
            d1p[i] += v[p][i].x*w1q.x + v[p][i].y*w1q.y + v[p][i].z*w1q.z + v[p][i].w*w1q.w;
            d2p[i] += v[p][i].x*w2q.x + v[p][i].y*w2q.y + v[p][i].z*w2q.z + v[p][i].w*w2q.w;
        }
    }

    #define TPOSE(P) { \
        u32 l0 = cvt_pk_bf16(v[P][0].x, v[P][1].x), h0 = cvt_pk_bf16(v[P][2].x, v[P][3].x); \
        *(uint2*)&tile[g][fq+0][m4] = (uint2){l0,h0}; \
        u32 l1 = cvt_pk_bf16(v[P][0].y, v[P][1].y), h1 = cvt_pk_bf16(v[P][2].y, v[P][3].y); \
        *(uint2*)&tile[g][fq+1][m4] = (uint2){l1,h1}; \
        u32 l2 = cvt_pk_bf16(v[P][0].z, v[P][1].z), h2 = cvt_pk_bf16(v[P][2].z, v[P][3].z); \
        *(uint2*)&tile[g][fq+2][m4] = (uint2){l2,h2}; \
        u32 l3 = cvt_pk_bf16(v[P][0].w, v[P][1].w), h3 = cvt_pk_bf16(v[P][2].w, v[P][3].w); \
        *(uint2*)&tile[g][fq+3][m4] = (uint2){l3,h3}; \
    }
    const int f_loc = tid2 >> 2;
    const int mo    = (tid2 & 3) * 16;
    #define XTOUT(P) { \
        uint4 q0 = *(const uint4*)&tile[g][f_loc][mo]; \
        uint4 q1 = *(const uint4*)&tile[g][f_loc][mo+8]; \
        u16* dst = XT + ((size_t)(b*F_ + (P*4+g)*64 + f_loc))*N_ + m0 + mo; \
        *(uint4*)dst = q0; *(uint4*)(dst+8) = q1; \
    }

    TPOSE(0)
    __syncthreads();
    XTOUT(0)
    __syncthreads();
    TPOSE(1)
    #pragma unroll
    for(int s2=1;s2<16;s2<<=1){
        #pragma unroll
        for(int i=0;i<4;i++){ d1p[i] += __shfl_xor(d1p[i],s2,64); d2p[i] += __shfl_xor(d2p[i],s2,64); }
    }
    if((t & 15) == 0){
        #pragma unroll
        for(int i=0;i<4;i++){ dpart[0][g][m4+i] = d1p[i]; dpart[1][g][m4+i] = d2p[i]; }
    }
    __syncthreads();
    XTOUT(1)
    if(t < 64){
        float s1 = dpart[0][0][t] + dpart[0][1][t] + dpart[0][2][t] + dpart[0][3][t];
        float s2 = dpart[1][0][t] + dpart[1][1][t] + dpart[1][2][t] + dpart[1][3][t];
        d1acc[b*N_ + m0 + t] = s1;
        d2acc[b*N_ + m0 + t] = s2;
    }
}

// ---- kernel 3: fused scores+softmax+PV+ELU, producer/consumer, 64-m chunks ----
// grid (16,16) = 256 blocks = 1/CU, 1024 threads = 16 waves. R5 structure with the
// period count HALVED: 16 iterations of 64-m chunks (R8 showed time ~ periods x serial;
// R5 showed deeper per-period work at constant periods wins).
// LDS: double-buffered 64 KB chunks (128 KB) + e2 4 KB + pbuf 16 KB = ~148 KB, 1 block/CU.
// Body VMEM/wave = 6 (4 gload_lds then 2 adj int2); "s_waitcnt vmcnt(2)" at loop top
// drains the distance-1 staged chunk, leaves the 2 newest adj loads in flight.
// Producer: wave wv -> rows (wv>>2 bin, (wv&3)*4+rowL), 4 P-values/lane/chunk (2 msubs).
// Consumer: (nsub, fq): 16 rows x 128 f, 2 msubs x 8 MFMA into shared acc[8] (K-accum).
__global__ __launch_bounds__(1024, 4)
void k_main(const u16* __restrict__ XT, const int* __restrict__ adj,
            const float* __restrict__ d1acc, const float* __restrict__ d2acc,
            float* __restrict__ out){
    __shared__ u16 xbuf[2][32768];     // 128 KB: [buf][fhalf*16384 + msub*8192 + c*512 + lane*8]
    __shared__ u32 lds_e2[N_];         // 4 KB exp(f2)/exp(.2 f2) bf16-pair table
    __shared__ u16 pbuf[2][4][1024];   // 16 KB P A-frags [buf][nsub][msub*512 + lane*8]
    __shared__ float dsums[64];        // row softmax denominators

    const int t    = threadIdx.x;
    const int lane = t & 63;
    const int wv   = t >> 6;           // 0..15
    const int nsub = wv & 3;           // consumer: row-group of 16
    const int fq   = wv >> 2;          // consumer: f-quarter of 128
    const int id   = blockIdx.x + (blockIdx.y << 4);
    const int xcd  = id & 7, slot = id >> 3;
    const int b    = (xcd << 1) | (slot >> 4);
    const int n0   = (slot & 15) << 6;
    const int r16  = lane & 15;
    const int quad = lane >> 4;
    const int rowL = lane >> 4;        // producer: row 0..3 within wave's quartet
    const int qL   = lane & 15;        // producer: col-pair index

    {
        float dv = d2acc[(size_t)b*N_ + t];
        lds_e2[t] = f2bf(__expf(dv)) | (f2bf(__expf(ALPHA*dv))<<16);
    }
    const float d1v  = d1acc[b*N_ + n0 + wv*4 + rowL];
    const float e1pL = __expf(d1v);
    const float e1nL = __expf(ALPHA*d1v);
    const int* adjLane = adj + ((size_t)(b*N_ + n0 + wv*4 + rowL))*N_ + qL*2;
    const u16* XTb = XT + (size_t)b*F_*N_;

    float dsum = 0.f;
    const int pOff = ((wv&3)*4 + rowL + (qL>>2)*16)*8 + (qL&3)*2;

    // P for 64-col chunk c -> pbuf[pb]: msub0 cols c*64+qL*2, msub1 cols c*64+32+qL*2
    auto produce = [&](int c, int pb, int2 adA, int2 adB){
        uint2 ev0 = *(const uint2*)(&lds_e2[c*64 + qL*2]);
        uint2 ev1 = *(const uint2*)(&lds_e2[c*64 + 32 + qL*2]);
        float p0 = fmaxf(e1pL*bflo(ev0.x), e1nL*bfhi(ev0.x)); p0 = adA.x ? p0 : 0.f;
        float p1 = fmaxf(e1pL*bflo(ev0.y), e1nL*bfhi(ev0.y)); p1 = adA.y ? p1 : 0.f;
        float p2 = fmaxf(e1pL*bflo(ev1.x), e1nL*bfhi(ev1.x)); p2 = adB.x ? p2 : 0.f;
        float p3 = fmaxf(e1pL*bflo(ev1.y), e1nL*bfhi(ev1.y)); p3 = adB.y ? p3 : 0.f;
        dsum += (p0+p1) + (p2+p3);
        *(u32*)(&pbuf[pb][wv>>2][pOff])       = cvt_pk_bf16(p0, p1);
        *(u32*)(&pbuf[pb][wv>>2][512 + pOff]) = cvt_pk_bf16(p2, p3);
    };
    // stage 64-m chunk (64 KB) at column mcol: 4 gload_lds per wave (64 segments total)
    auto stage = [&](int mcol, u16* buf){
        #pragma unroll
        for(int k=0;k<4;k++){
            int idx = wv*4 + k;                 // 0..63
            int fhh = idx>>5, msub = (idx>>4)&1, c = idx&15;
            const u16* g = XTb + (size_t)(fhh*256 + c*16 + r16)*N_ + mcol + msub*32 + quad*8;
            gload_lds16(g, buf + fhh*16384 + msub*8192 + c*512);
        }
    };

    __syncthreads();                       // lds_e2 ready
    {
        int2 a0 = *(const int2*)(adjLane);
        int2 a1 = *(const int2*)(adjLane + 32);
        produce(0, 0, a0, a1);
    }
    stage(0, xbuf[0]);
    int2 adUa = *(const int2*)(adjLane + 64);   // adj chunk 1
    int2 adUb = *(const int2*)(adjLane + 96);
    asm volatile("s_waitcnt lgkmcnt(0)" ::: "memory");
    __syncthreads();                       // P[0] + chunk 0 resident (full drain, one-time)

    float4v acc[8];
    #pragma unroll
    for(int i=0;i<8;i++) acc[i] = (float4v){0.f,0.f,0.f,0.f};

    int db = 0;
    for(int i=0;i<16;i++){
        // chunk i staged last body (4 ops) + 2 adj in flight: drain stages, keep adj
        asm volatile("s_waitcnt vmcnt(2) lgkmcnt(0)\n\ts_barrier" ::: "memory");

        if(i < 15) stage((i+1)*64, xbuf[db^1]);          // distance-1 staging (4 ops)
        const int mc2 = (i < 14) ? (i+2)*64 : 0;         // adj distance-2 (dummy wrap tail)
        int2 adVa = *(const int2*)(adjLane + mc2);
        int2 adVb = *(const int2*)(adjLane + mc2 + 32);
        if(i < 15) produce(i+1, (i+1)&1, adUa, adUb);    // P[i+1] from adj[i+1]

        #pragma unroll
        for(int msub=0; msub<2; msub++){
            Frag af;
            { uint4 aw = *(const uint4*)(&pbuf[i&1][nsub][msub*512 + lane*8]);
              af.u[0]=aw.x; af.u[1]=aw.y; af.u[2]=aw.z; af.u[3]=aw.w; }
            const u16* bb = &xbuf[db][(fq>>1)*16384 + msub*8192 + (fq&1)*4096 + lane*8];
            #pragma unroll
            for(int ct=0; ct<8; ct++){
                uint4 bw = *(const uint4*)(bb + ct*512);
                Frag bf_; bf_.u[0]=bw.x; bf_.u[1]=bw.y; bf_.u[2]=bw.z; bf_.u[3]=bw.w;
                acc[ct] = __builtin_amdgcn_mfma_f32_16x16x32_bf16(af.s, bf_.s, acc[ct], 0, 0, 0);
            }
        }
        adUa = adVa; adUb = adVb;
        db ^= 1;
    }

    // ---- softmax denominators: reduce over qL (lane bits 0..3) ----
    asm volatile("s_waitcnt vmcnt(0) lgkmcnt(0)" ::: "memory");   // drain tail dummy loads
    dsum += __shfl_xor(dsum, 1, 64);
    dsum += __shfl_xor(dsum, 2, 64);
    dsum += __shfl_xor(dsum, 4, 64);
    dsum += __shfl_xor(dsum, 8, 64);
    if(qL == 0) dsums[wv*4 + rowL] = dsum;
    __syncthreads();
    float invr[4];
    #pragma unroll
    for(int r=0;r<4;r++) invr[r] = 1.0f / fmaxf(dsums[nsub*16 + quad*4 + r], 1e-30f);

    // ---- epilogue: scale, ELU, fp32 store ----
    #pragma unroll
    for(int ct=0; ct<8; ct++){
        #pragma unroll
        for(int r=0;r<4;r++){
            float v = acc[ct][r] * invr[r];
            v = (v > 0.f) ? v : (__expf(v) - 1.f);
            int n_out = n0 + nsub*16 + quad*4 + r;
            out[((size_t)(b*N_ + n_out))*F_ + fq*128 + ct*16 + r16] = v;
        }
    }
}

extern "C" void kernel_launch(void* const* d_in, const int* in_sizes, int n_in,
                              void* d_out, int out_size, void* d_ws, size_t ws_size,
                              hipStream_t stream) {
    const float* X  = (const float*)d_in[0];   // [16,1024,512] fp32
    const int* adj  = (const int*)d_in[1];     // [16,1024,1024] int32
    const float* W  = (const float*)d_in[2];   // [512,512] fp32
    const float* a1 = (const float*)d_in[3];   // [512]
    const float* a2 = (const float*)d_in[4];   // [512]
    float* out = (float*)d_out;                // [16,1024,512] fp32

    float* ws    = (float*)d_ws;
    float* d1acc = ws + 1024;                  // fully written by k_prep (no memset needed)
    float* d2acc = ws + 1024 + 16384;
    u16*  XT     = (u16*)(ws + 50176);         // 16.78 MB bf16 [b][f][m]

    hipMemsetAsync(ws, 0, 1024*sizeof(float), stream);    // zero w1/w2 only
    k_w12<<<64, 256, 0, stream>>>(W, a1, a2, ws);
    k_prep<<<dim3(16, 16), 1024, 0, stream>>>(X, ws, XT, d1acc, d2acc);
    k_main<<<dim3(16, 16), 1024, 0, stream>>>(XT, adj, d1acc, d2acc, out);
}

// Round 11
// 174.171 us; speedup vs baseline: 1.0841x; 1.0841x over previous
//
#include <hip/hip_runtime.h>
#include <stdint.h>

typedef unsigned int u32;
typedef unsigned short u16;

#define N_  1024
#define F_  512
#define ALPHA 0.2f
#define TSTR2 72   // k_prep LDS tile stride (u16): 144 B rows -> 16B-aligned b128 reads, 2-way (free)

typedef __attribute__((ext_vector_type(8))) short short8;
typedef __attribute__((ext_vector_type(4))) float float4v;

union Frag { short8 s; u32 u[4]; };

static __device__ __forceinline__ float bits2f(u32 b){ union{u32 u; float f;} c; c.u=b; return c.f; }
static __device__ __forceinline__ u32   f2bits(float f){ union{float f_; u32 u;} c; c.f_=f; return c.u; }
static __device__ __forceinline__ float bflo(u32 p){ return bits2f(p<<16); }
static __device__ __forceinline__ float bfhi(u32 p){ return bits2f(p & 0xffff0000u); }
static __device__ __forceinline__ u32   f2bf(float f){ u32 u=f2bits(f); return (u + 0x7fffu + ((u>>16)&1u))>>16; }
static __device__ __forceinline__ u32   cvt_pk_bf16(float lo, float hi){
    u32 r; asm("v_cvt_pk_bf16_f32 %0, %1, %2" : "=v"(r) : "v"(lo), "v"(hi)); return r;
}
static __device__ __forceinline__ short8 u2s8(uint4 u){ Frag f; f.u[0]=u.x; f.u[1]=u.y; f.u[2]=u.z; f.u[3]=u.w; return f.s; }

// ---- kernel 1: w1 = W^T a1, w2 = W^T a2 (atomic partial sums into ws[0..1024)) ----
__global__ void k_w12(const float* __restrict__ W, const float* __restrict__ a1,
                      const float* __restrict__ a2, float* __restrict__ ws){
    int t = threadIdx.x;          // 256 threads: f = t and t+256
    int bo = blockIdx.x;          // 64 blocks: o-chunk of 8
    float s1a=0.f,s2a=0.f,s1b=0.f,s2b=0.f;
    #pragma unroll
    for(int i=0;i<8;i++){
        int o = bo*8+i;
        float av1 = a1[o], av2 = a2[o];
        float wa = W[o*F_ + t], wb = W[o*F_ + t + 256];
        s1a += wa*av1; s2a += wa*av2; s1b += wb*av1; s2b += wb*av2;
    }
    atomicAdd(&ws[t],       s1a); atomicAdd(&ws[512+t],     s2a);
    atomicAdd(&ws[t+256],   s1b); atomicAdd(&ws[512+t+256], s2b);
}

// ---- kernel 2: transpose X->XT bf16 + d1/d2 dots (R9 known-good, no atomics) ----
__global__ __launch_bounds__(1024)
void k_prep(const float* __restrict__ X, const float* __restrict__ ws,
            u16* __restrict__ XT, float* __restrict__ d1acc, float* __restrict__ d2acc){
    __shared__ u16 tile[4][64][TSTR2];   // 36 KB: [slice-group][f 64][m 64 +pad]
    __shared__ float dpart[2][4][64];    // 2 KB group-partial row dots

    const int t   = threadIdx.x;
    const int id  = blockIdx.x + (blockIdx.y << 4);   // 0..255
    const int xcd = id & 7, slot = id >> 3;
    const int b   = (xcd << 1) | (slot >> 4);
    const int m0  = (slot & 15) << 6;

    const int g    = t >> 8;             // slice group 0..3
    const int tid2 = t & 255;
    const int mg   = tid2 >> 4;          // 0..15
    const int m4   = mg * 4;
    const int fq   = (tid2 & 15) * 4;

    float4 v[2][4];
    #pragma unroll
    for(int p=0;p<2;p++){
        const float* Xb = X + ((size_t)(b*N_ + m0 + m4))*F_ + (p*4+g)*64 + fq;
        #pragma unroll
        for(int i=0;i<4;i++) v[p][i] = *(const float4*)(Xb + (size_t)i*F_);
    }

    float d1p[4]={0.f,0.f,0.f,0.f}, d2p[4]={0.f,0.f,0.f,0.f};
    #pragma unroll
    for(int p=0;p<2;p++){
        float4 w1q = *(const float4*)(ws + (p*4+g)*64 + fq);
        float4 w2q = *(const float4*)(ws + 512 + (p*4+g)*64 + fq);
        #pragma unroll
        for(int i=0;i<4;i++){
            d1p[i] += v[p][i].x*w1q.x + v[p][i].y*w1q.y + v[p][i].z*w1q.z + v[p][i].w*w1q.w;
            d2p[i] += v[p][i].x*w2q.x + v[p][i].y*w2q.y + v[p][i].z*w2q.z + v[p][i].w*w2q.w;
        }
    }

    #define TPOSE(P) { \
        u32 l0 = cvt_pk_bf16(v[P][0].x, v[P][1].x), h0 = cvt_pk_bf16(v[P][2].x, v[P][3].x); \
        *(uint2*)&tile[g][fq+0][m4] = (uint2){l0,h0}; \
        u32 l1 = cvt_pk_bf16(v[P][0].y, v[P][1].y), h1 = cvt_pk_bf16(v[P][2].y, v[P][3].y); \
        *(uint2*)&tile[g][fq+1][m4] = (uint2){l1,h1}; \
        u32 l2 = cvt_pk_bf16(v[P][0].z, v[P][1].z), h2 = cvt_pk_bf16(v[P][2].z, v[P][3].z); \
        *(uint2*)&tile[g][fq+2][m4] = (uint2){l2,h2}; \
        u32 l3 = cvt_pk_bf16(v[P][0].w, v[P][1].w), h3 = cvt_pk_bf16(v[P][2].w, v[P][3].w); \
        *(uint2*)&tile[g][fq+3][m4] = (uint2){l3,h3}; \
    }
    const int f_loc = tid2 >> 2;
    const int mo    = (tid2 & 3) * 16;
    #define XTOUT(P) { \
        uint4 q0 = *(const uint4*)&tile[g][f_loc][mo]; \
        uint4 q1 = *(const uint4*)&tile[g][f_loc][mo+8]; \
        u16* dst = XT + ((size_t)(b*F_ + (P*4+g)*64 + f_loc))*N_ + m0 + mo; \
        *(uint4*)dst = q0; *(uint4*)(dst+8) = q1; \
    }

    TPOSE(0)
    __syncthreads();
    XTOUT(0)
    __syncthreads();
    TPOSE(1)
    #pragma unroll
    for(int s2=1;s2<16;s2<<=1){
        #pragma unroll
        for(int i=0;i<4;i++){ d1p[i] += __shfl_xor(d1p[i],s2,64); d2p[i] += __shfl_xor(d2p[i],s2,64); }
    }
    if((t & 15) == 0){
        #pragma unroll
        for(int i=0;i<4;i++){ dpart[0][g][m4+i] = d1p[i]; dpart[1][g][m4+i] = d2p[i]; }
    }
    __syncthreads();
    XTOUT(1)
    if(t < 64){
        float s1 = dpart[0][0][t] + dpart[0][1][t] + dpart[0][2][t] + dpart[0][3][t];
        float s2 = dpart[1][0][t] + dpart[1][1][t] + dpart[1][2][t] + dpart[1][3][t];
        d1acc[b*N_ + m0 + t] = s1;
        d2acc[b*N_ + m0 + t] = s2;
    }
}

// ---- kernel 3: 2-barrier k_main: materialized P + direct-from-L2 B ----
// grid (16,16) = 256 blocks = 1/CU, 1024 threads = 16 waves. LDS 135 KB (pbuf 128 + e2 4).
// PHASE 1 (HBM-bound, ~adj stream): all 16 waves produce the FULL P (64 rows x 1024 m,
//   bf16 A-fragments) into pbuf + per-row dsums. adj loads batched x4 for MLP. 1 barrier.
// PHASE 2 (barrier-free, software-pipelined): wave fqq owns a 64-row x 32-f strip.
//   Per chunk i: 4 pbuf ds_read_b128 (A for nsub 0..3) + 2 global dwordx4 (B direct from
//   XT in L2 -- XCD affinity makes XT[b] L2-resident; each XT byte read ONCE per block)
//   + 8 MFMA into acc[4][2]. Manual even/odd double-buffer, all static indexing.
// LDS reads: 64 b128/chunk (vs 144 staged) and NO staging writes, NO per-chunk barriers.
__global__ __launch_bounds__(1024, 4)
void k_main(const u16* __restrict__ XT, const int* __restrict__ adj,
            const float* __restrict__ d1acc, const float* __restrict__ d2acc,
            float* __restrict__ out){
    __shared__ u16 pbuf[32][4][512];   // 128 KB: P A-frags [chunk][nsub][lane*8]
    __shared__ u32 lds_e2[N_];         // 4 KB exp(f2)/exp(.2 f2) bf16-pair table
    __shared__ float dsums[64];        // row softmax denominators

    const int t    = threadIdx.x;
    const int lane = t & 63;
    const int wv   = t >> 6;           // 0..15
    const int fqq  = wv;               // consumer: f-slice of 32 (0..15)
    const int id   = blockIdx.x + (blockIdx.y << 4);
    const int xcd  = id & 7, slot = id >> 3;
    const int b    = (xcd << 1) | (slot >> 4);
    const int n0   = (slot & 15) << 6;
    const int r16  = lane & 15;
    const int quad = lane >> 4;
    const int rowL = lane >> 4;        // producer: row 0..3 within wave's quartet
    const int qL   = lane & 15;        // producer: col-pair index

    // exp(f2)/exp(.2*f2) bf16-pair table: 1 entry/thread
    {
        float dv = d2acc[(size_t)b*N_ + t];
        lds_e2[t] = f2bf(__expf(dv)) | (f2bf(__expf(ALPHA*dv))<<16);
    }
    const float d1v  = d1acc[b*N_ + n0 + wv*4 + rowL];
    const float e1pL = __expf(d1v);
    const float e1nL = __expf(ALPHA*d1v);
    const int* adjLane = adj + ((size_t)(b*N_ + n0 + wv*4 + rowL))*N_ + qL*2;
    const u16* XTb = XT + (size_t)b*F_*N_;

    float dsum = 0.f;
    const int pOff = ((wv&3)*4 + rowL + (qL>>2)*16)*8 + (qL&3)*2;

    auto produce = [&](int c, int2 ad){
        uint2 ev = *(const uint2*)(&lds_e2[c*32 + qL*2]);
        float p0 = fmaxf(e1pL*bflo(ev.x), e1nL*bfhi(ev.x)); p0 = ad.x ? p0 : 0.f;
        float p1 = fmaxf(e1pL*bflo(ev.y), e1nL*bfhi(ev.y)); p1 = ad.y ? p1 : 0.f;
        dsum += p0 + p1;
        *(u32*)(&pbuf[c][wv>>2][pOff]) = cvt_pk_bf16(p0, p1);
    };

    __syncthreads();                       // lds_e2 visible

    // ---- PHASE 1: produce all P (4-batched adj loads for MLP) ----
    #pragma unroll
    for(int g4 = 0; g4 < 8; g4++){
        int2 q0 = *(const int2*)(adjLane + (g4*4+0)*32);
        int2 q1 = *(const int2*)(adjLane + (g4*4+1)*32);
        int2 q2 = *(const int2*)(adjLane + (g4*4+2)*32);
        int2 q3 = *(const int2*)(adjLane + (g4*4+3)*32);
        produce(g4*4+0, q0);
        produce(g4*4+1, q1);
        produce(g4*4+2, q2);
        produce(g4*4+3, q3);
    }
    // per-row softmax denominators (reduce over qL = lane bits 0..3)
    dsum += __shfl_xor(dsum, 1, 64);
    dsum += __shfl_xor(dsum, 2, 64);
    dsum += __shfl_xor(dsum, 4, 64);
    dsum += __shfl_xor(dsum, 8, 64);
    if(qL == 0) dsums[wv*4 + rowL] = dsum;

    __syncthreads();                       // pbuf + dsums visible; ONLY other barrier

    // ---- PHASE 2: barrier-free pipelined MFMA sweep ----
    float4v acc[4][2];
    #pragma unroll
    for(int ns=0;ns<4;ns++){ acc[ns][0]=(float4v){0,0,0,0}; acc[ns][1]=(float4v){0,0,0,0}; }

    const u16* pA  = &pbuf[0][0][0];
    const u16* bB0 = XTb + (size_t)(fqq*32 +      r16)*N_ + quad*8;   // ct=0 rows
    const u16* bB1 = XTb + (size_t)(fqq*32 + 16 + r16)*N_ + quad*8;   // ct=1 rows

    #define LDCH(Aa,Ab,Ac,Ad,Bx,By,I) \
        Aa = *(const uint4*)(pA + ((I)*4+0)*512 + lane*8); \
        Ab = *(const uint4*)(pA + ((I)*4+1)*512 + lane*8); \
        Ac = *(const uint4*)(pA + ((I)*4+2)*512 + lane*8); \
        Ad = *(const uint4*)(pA + ((I)*4+3)*512 + lane*8); \
        Bx = *(const uint4*)(bB0 + (I)*32); \
        By = *(const uint4*)(bB1 + (I)*32);

    #define STEP(Aa,Ab,Ac,Ad,Bx,By) { \
        short8 sb0 = u2s8(Bx), sb1 = u2s8(By); \
        acc[0][0] = __builtin_amdgcn_mfma_f32_16x16x32_bf16(u2s8(Aa), sb0, acc[0][0],0,0,0); \
        acc[0][1] = __builtin_amdgcn_mfma_f32_16x16x32_bf16(u2s8(Aa), sb1, acc[0][1],0,0,0); \
        acc[1][0] = __builtin_amdgcn_mfma_f32_16x16x32_bf16(u2s8(Ab), sb0, acc[1][0],0,0,0); \
        acc[1][1] = __builtin_amdgcn_mfma_f32_16x16x32_bf16(u2s8(Ab), sb1, acc[1][1],0,0,0); \
        acc[2][0] = __builtin_amdgcn_mfma_f32_16x16x32_bf16(u2s8(Ac), sb0, acc[2][0],0,0,0); \
        acc[2][1] = __builtin_amdgcn_mfma_f32_16x16x32_bf16(u2s8(Ac), sb1, acc[2][1],0,0,0); \
        acc[3][0] = __builtin_amdgcn_mfma_f32_16x16x32_bf16(u2s8(Ad), sb0, acc[3][0],0,0,0); \
        acc[3][1] = __builtin_amdgcn_mfma_f32_16x16x32_bf16(u2s8(Ad), sb1, acc[3][1],0,0,0); \
    }

    uint4 A0,A1,A2,A3,B0,B1;        // even set
    uint4 C0,C1,C2,C3,D0,D1;        // odd set
    LDCH(A0,A1,A2,A3,B0,B1, 0)
    for(int i = 0; i < 32; i += 2){
        LDCH(C0,C1,C2,C3,D0,D1, i+1)          // prefetch odd chunk
        STEP(A0,A1,A2,A3,B0,B1)               // compute even chunk
        if(i < 30){ LDCH(A0,A1,A2,A3,B0,B1, i+2) }   // prefetch next even
        STEP(C0,C1,C2,C3,D0,D1)               // compute odd chunk
    }

    // ---- epilogue: scale, ELU, fp32 store ----
    float invv[4][4];
    #pragma unroll
    for(int ns=0;ns<4;ns++)
        #pragma unroll
        for(int r=0;r<4;r++)
            invv[ns][r] = 1.0f / fmaxf(dsums[ns*16 + quad*4 + r], 1e-30f);

    #pragma unroll
    for(int ns=0;ns<4;ns++){
        #pragma unroll
        for(int ct=0;ct<2;ct++){
            #pragma unroll
            for(int r=0;r<4;r++){
                float v = acc[ns][ct][r] * invv[ns][r];
                v = (v > 0.f) ? v : (__expf(v) - 1.f);
                int n_out = n0 + ns*16 + quad*4 + r;
                out[((size_t)(b*N_ + n_out))*F_ + fqq*32 + ct*16 + r16] = v;
            }
        }
    }
    #undef LDCH
    #undef STEP
}

extern "C" void kernel_launch(void* const* d_in, const int* in_sizes, int n_in,
                              void* d_out, int out_size, void* d_ws, size_t ws_size,
                              hipStream_t stream) {
    const float* X  = (const float*)d_in[0];   // [16,1024,512] fp32
    const int* adj  = (const int*)d_in[1];     // [16,1024,1024] int32
    const float* W  = (const float*)d_in[2];   // [512,512] fp32
    const float* a1 = (const float*)d_in[3];   // [512]
    const float* a2 = (const float*)d_in[4];   // [512]
    float* out = (float*)d_out;                // [16,1024,512] fp32

    float* ws    = (float*)d_ws;
    float* d1acc = ws + 1024;                  // fully written by k_prep (no memset needed)
    float* d2acc = ws + 1024 + 16384;
    u16*  XT     = (u16*)(ws + 50176);         // 16.78 MB bf16 [b][f][m]

    hipMemsetAsync(ws, 0, 1024*sizeof(float), stream);    // zero w1/w2 only
    k_w12<<<64, 256, 0, stream>>>(W, a1, a2, ws);
    k_prep<<<dim3(16, 16), 1024, 0, stream>>>(X, ws, XT, d1acc, d2acc);
    k_main<<<dim3(16, 16), 1024, 0, stream>>>(XT, adj, d1acc, d2acc, out);
}